// Round 1
// baseline (243.362 us; speedup 1.0000x reference)
//
#include <hip/hip_runtime.h>

// RNMF encoder, MI355X. Key identities:
//   b_k = b_0 + H z_k  (ISTA scan telescopes) => z <- relu(b0 + H z - t), 16x
//   H z = [(1-0.1*eta) z_q - eta*D^T(u+z_m) ; (1-1.1*eta) z_m - eta*u], u = D z_q
// so only D (256x64) is needed. eta = 1/lambda_max(D^T D) from on-device power
// method (G -> G^8 squarings + 28 iters; >= reference's 100 G-multiplies).

typedef __bf16 bf16x8 __attribute__((ext_vector_type(8)));
typedef float f32x4 __attribute__((ext_vector_type(4)));

#define MFMA16(a, b, c) __builtin_amdgcn_mfma_f32_16x16x32_bf16((a), (b), (c), 0, 0, 0)

#define NTOT 65536
#define NCOL 32

__device__ __forceinline__ unsigned pk2(float a, float b) {
  unsigned short ua = __builtin_bit_cast(unsigned short, (__bf16)a);
  unsigned short ub = __builtin_bit_cast(unsigned short, (__bf16)b);
  return (unsigned)ua | ((unsigned)ub << 16);
}

// ---------------- Kernel 0: prep (1 block, 256 threads) ----------------
// ws layout: [0..255] floats/bytes header (wsf[0]=eta), +256: Dbf [256][64] bf16,
// +256+32768: DTbf [64][256] bf16.
__global__ void rnmf_prep(const float* __restrict__ D, void* __restrict__ ws) {
  float* wsf = (float*)ws;
  __bf16* Dbf = (__bf16*)((char*)ws + 256);
  __bf16* DTbf = (__bf16*)((char*)ws + 256 + 32768);

  __shared__ __bf16 DTl[64 * 264];   // D^T, [a][k] stride 264
  __shared__ __bf16 gA[64 * 72];     // G buffers (bf16), stride 72
  __shared__ __bf16 gB[64 * 72];
  __shared__ float gf[64 * 68];      // G^8 fp32, stride 68
  __shared__ __align__(16) float xv[64];

  const int tid = threadIdx.x;
  const int w = tid >> 6, lane = tid & 63, c = lane & 15, q4 = lane >> 4;

  // D -> bf16 (row-major) out to ws, coalesced
#pragma unroll
  for (int e = 0; e < 16; ++e) {
    int i4 = e * 256 + tid;                       // float4 index, 4096 total
    float4 dv = *(const float4*)(D + i4 * 4);
    uint2 u; u.x = pk2(dv.x, dv.y); u.y = pk2(dv.z, dv.w);
    *(uint2*)(Dbf + i4 * 4) = u;
  }
  // D^T into LDS (bf16)
#pragma unroll
  for (int e = 0; e < 64; ++e) {
    int flat = e * 256 + tid;                     // 0..16383
    int k = flat >> 6, a = flat & 63;
    DTl[a * 264 + k] = (__bf16)D[k * 64 + a];
  }
  __syncthreads();
  // D^T bf16 out to ws
#pragma unroll
  for (int e = 0; e < 8; ++e) {
    int fi = e * 256 + tid;                       // frag idx, elem = fi*8
    int a = fi >> 5;
    int k = (fi * 8) & 255;
    *(bf16x8*)(DTbf + fi * 8) = *(const bf16x8*)&DTl[a * 264 + k];
  }
  // G = D^T D via MFMA (wave w owns q-row tile w). G is symmetric, so the
  // row-major bf16 buffer serves both A and B fragment reads.
#pragma unroll
  for (int ct = 0; ct < 4; ++ct) {
    f32x4 acc = {0.f, 0.f, 0.f, 0.f};
#pragma unroll
    for (int kb = 0; kb < 8; ++kb) {
      bf16x8 a = *(const bf16x8*)&DTl[(16 * w + c) * 264 + 32 * kb + 8 * q4];
      bf16x8 b = *(const bf16x8*)&DTl[(16 * ct + c) * 264 + 32 * kb + 8 * q4];
      acc = MFMA16(a, b, acc);
    }
#pragma unroll
    for (int r = 0; r < 4; ++r)
      gA[(16 * w + 4 * q4 + r) * 72 + 16 * ct + c] = (__bf16)acc[r];
  }
  __syncthreads();
  // G2 = G*G  (gA -> gB)
#pragma unroll
  for (int ct = 0; ct < 4; ++ct) {
    f32x4 acc = {0.f, 0.f, 0.f, 0.f};
#pragma unroll
    for (int kb = 0; kb < 2; ++kb) {
      bf16x8 a = *(const bf16x8*)&gA[(16 * w + c) * 72 + 32 * kb + 8 * q4];
      bf16x8 b = *(const bf16x8*)&gA[(16 * ct + c) * 72 + 32 * kb + 8 * q4];
      acc = MFMA16(a, b, acc);
    }
#pragma unroll
    for (int r = 0; r < 4; ++r)
      gB[(16 * w + 4 * q4 + r) * 72 + 16 * ct + c] = (__bf16)acc[r];
  }
  __syncthreads();
  // G4 (gB -> gA)
#pragma unroll
  for (int ct = 0; ct < 4; ++ct) {
    f32x4 acc = {0.f, 0.f, 0.f, 0.f};
#pragma unroll
    for (int kb = 0; kb < 2; ++kb) {
      bf16x8 a = *(const bf16x8*)&gB[(16 * w + c) * 72 + 32 * kb + 8 * q4];
      bf16x8 b = *(const bf16x8*)&gB[(16 * ct + c) * 72 + 32 * kb + 8 * q4];
      acc = MFMA16(a, b, acc);
    }
#pragma unroll
    for (int r = 0; r < 4; ++r)
      gA[(16 * w + 4 * q4 + r) * 72 + 16 * ct + c] = (__bf16)acc[r];
  }
  __syncthreads();
  // G8 (gA -> gf, fp32)
#pragma unroll
  for (int ct = 0; ct < 4; ++ct) {
    f32x4 acc = {0.f, 0.f, 0.f, 0.f};
#pragma unroll
    for (int kb = 0; kb < 2; ++kb) {
      bf16x8 a = *(const bf16x8*)&gA[(16 * w + c) * 72 + 32 * kb + 8 * q4];
      bf16x8 b = *(const bf16x8*)&gA[(16 * ct + c) * 72 + 32 * kb + 8 * q4];
      acc = MFMA16(a, b, acc);
    }
#pragma unroll
    for (int r = 0; r < 4; ++r)
      gf[(16 * w + 4 * q4 + r) * 68 + 16 * ct + c] = acc[r];
  }
  __syncthreads();

  // power method on B = G8/trace(G8), wave 0 only (no barriers below)
  if (w == 0) {
    float td = gf[lane * 68 + lane];
#pragma unroll
    for (int off = 32; off; off >>= 1) td += __shfl_xor(td, off, 64);
    const float tr = td;
    const float itr = 1.f / tr;
    xv[lane] = 1.f;
    float nm = 1.f;
    for (int itp = 0; itp < 28; ++itp) {
      float acc = 0.f;
#pragma unroll
      for (int k = 0; k < 64; k += 4) {
        float4 g = *(const float4*)&gf[lane * 68 + k];
        float4 xx = *(const float4*)&xv[k];
        acc = fmaf(g.x, xx.x, acc);
        acc = fmaf(g.y, xx.y, acc);
        acc = fmaf(g.z, xx.z, acc);
        acc = fmaf(g.w, xx.w, acc);
      }
      float y = acc * itr;
      float n2 = y * y;
#pragma unroll
      for (int off = 32; off; off >>= 1) n2 += __shfl_xor(n2, off, 64);
      nm = sqrtf(n2);
      xv[lane] = y / nm;
    }
    if (lane == 0) wsf[0] = 1.f / powf(nm * tr, 0.125f);  // eta = 1/alpha
  }
}

// ---------------- Kernel 1: main (2048 blocks x 256 thr, 32 cols/block) -----
__global__ __launch_bounds__(256, 2) void rnmf_main(const float* __restrict__ X,
                                                    float* __restrict__ Z,
                                                    const void* __restrict__ ws) {
  const float* wsf = (const float*)ws;
  const __bf16* Dbf = (const __bf16*)((const char*)ws + 256);
  const __bf16* DTbf = (const __bf16*)((const char*)ws + 256 + 32768);

  __shared__ __bf16 zqb[32 * 72];    // z_q bf16, [col][k], stride 72
  __shared__ __bf16 vb[32 * 264];    // V = u + z_m bf16, [col][k], stride 264
  __shared__ float xs[32 * 260];     // X tile fp32, [col][row], stride 260

  const int tid = threadIdx.x;
  const int w = tid >> 6;            // wave 0..3
  const int lane = tid & 63;
  const int c = lane & 15;           // MFMA col / A-row lane
  const int q4 = lane >> 4;          // MFMA quad
  const int j0 = blockIdx.x * NCOL;

  // stage X tile (coalesced global, col-major LDS)
#pragma unroll
  for (int e = 0; e < 32; ++e) {
    int flat = e * 256 + tid;        // 0..8191
    int row = flat >> 5, col = flat & 31;
    xs[col * 260 + row] = X[row * NTOT + j0 + col];
  }

  const float eta = wsf[0];
  const float cq = 1.f - 0.1f * eta;   // 1 - eta*lambda_star
  const float cm = 1.f - 1.1f * eta;   // 1 - eta*(1+lambda_star)
  const float tm = 0.1f * eta;         // lambda_o * eta

  // preload D fragments (iteration-invariant, live in VGPRs)
  bf16x8 d1[4][2];                     // GEMM1 A: D rows [64w..64w+64), K=64
#pragma unroll
  for (int rt = 0; rt < 4; ++rt)
#pragma unroll
    for (int kb = 0; kb < 2; ++kb)
      d1[rt][kb] = *(const bf16x8*)(Dbf + (64 * w + 16 * rt + c) * 64 + 32 * kb + 8 * q4);
  bf16x8 d2[8];                        // GEMM2 A: D^T rows [16w..16w+16), K=256
#pragma unroll
  for (int kb = 0; kb < 8; ++kb)
    d2[kb] = *(const bf16x8*)(DTbf + (16 * w + c) * 256 + 32 * kb + 8 * q4);

  __syncthreads();

  // b0_q = eta * D^T x  (MFMA over bf16-cast X from LDS)
  float bqt[2][4];
#pragma unroll
  for (int ct = 0; ct < 2; ++ct) {
    f32x4 acc = {0.f, 0.f, 0.f, 0.f};
#pragma unroll
    for (int kb = 0; kb < 8; ++kb) {
      const float* p = &xs[(16 * ct + c) * 260 + 32 * kb + 8 * q4];
      float4 lo = *(const float4*)p;
      float4 hi = *(const float4*)(p + 4);
      bf16x8 bf;
      bf[0] = (__bf16)lo.x; bf[1] = (__bf16)lo.y; bf[2] = (__bf16)lo.z; bf[3] = (__bf16)lo.w;
      bf[4] = (__bf16)hi.x; bf[5] = (__bf16)hi.y; bf[6] = (__bf16)hi.z; bf[7] = (__bf16)hi.w;
      acc = MFMA16(d2[kb], bf, acc);
    }
#pragma unroll
    for (int r = 0; r < 4; ++r) bqt[ct][r] = eta * acc[r];   // t_q = 0
  }

  // b0_m - t_m = eta*x - tm  (exact fp32)
  float bmt[4][2][4];
#pragma unroll
  for (int rt = 0; rt < 4; ++rt)
#pragma unroll
    for (int ct = 0; ct < 2; ++ct) {
      const float* p = &xs[(16 * ct + c) * 260 + 64 * w + 16 * rt + 4 * q4];
      float4 v = *(const float4*)p;
      bmt[rt][ct][0] = fmaf(eta, v.x, -tm);
      bmt[rt][ct][1] = fmaf(eta, v.y, -tm);
      bmt[rt][ct][2] = fmaf(eta, v.z, -tm);
      bmt[rt][ct][3] = fmaf(eta, v.w, -tm);
    }

  // z1 = relu(b0 - t)
  float zq[2][4], zm[4][2][4];
#pragma unroll
  for (int ct = 0; ct < 2; ++ct)
#pragma unroll
    for (int r = 0; r < 4; ++r) zq[ct][r] = fmaxf(bqt[ct][r], 0.f);
#pragma unroll
  for (int rt = 0; rt < 4; ++rt)
#pragma unroll
    for (int ct = 0; ct < 2; ++ct)
#pragma unroll
      for (int r = 0; r < 4; ++r) zm[rt][ct][r] = fmaxf(bmt[rt][ct][r], 0.f);

  // publish z_q for iteration 1
#pragma unroll
  for (int ct = 0; ct < 2; ++ct) {
    uint2 u; u.x = pk2(zq[ct][0], zq[ct][1]); u.y = pk2(zq[ct][2], zq[ct][3]);
    *(uint2*)&zqb[(16 * ct + c) * 72 + 16 * w + 4 * q4] = u;
  }

  for (int it = 0; it < 15; ++it) {
    __syncthreads();   // zqb ready; vb free
    // GEMM1: U = D z_q ; then z_m update + V publish
#pragma unroll
    for (int ct = 0; ct < 2; ++ct) {
      bf16x8 bz0 = *(const bf16x8*)&zqb[(16 * ct + c) * 72 + 8 * q4];
      bf16x8 bz1 = *(const bf16x8*)&zqb[(16 * ct + c) * 72 + 32 + 8 * q4];
#pragma unroll
      for (int rt = 0; rt < 4; ++rt) {
        f32x4 acc = {0.f, 0.f, 0.f, 0.f};
        acc = MFMA16(d1[rt][0], bz0, acc);
        acc = MFMA16(d1[rt][1], bz1, acc);
        float vv[4];
#pragma unroll
        for (int r = 0; r < 4; ++r) {
          float u = acc[r];
          float zo = zm[rt][ct][r];
          vv[r] = u + zo;                              // V = u + z_m (old)
          float zn = fmaf(cm, zo, bmt[rt][ct][r]);
          zn = fmaf(-eta, u, zn);
          zm[rt][ct][r] = fmaxf(zn, 0.f);
        }
        uint2 uu; uu.x = pk2(vv[0], vv[1]); uu.y = pk2(vv[2], vv[3]);
        *(uint2*)&vb[(16 * ct + c) * 264 + 64 * w + 16 * rt + 4 * q4] = uu;
      }
    }
    __syncthreads();   // vb ready; zqb free
    // GEMM2: Wq = D^T V ; z_q update + publish
#pragma unroll
    for (int ct = 0; ct < 2; ++ct) {
      f32x4 acc = {0.f, 0.f, 0.f, 0.f};
#pragma unroll
      for (int kb = 0; kb < 8; ++kb) {
        bf16x8 bv = *(const bf16x8*)&vb[(16 * ct + c) * 264 + 32 * kb + 8 * q4];
        acc = MFMA16(d2[kb], bv, acc);
      }
#pragma unroll
      for (int r = 0; r < 4; ++r) {
        float zn = fmaf(cq, zq[ct][r], bqt[ct][r]);
        zn = fmaf(-eta, acc[r], zn);
        zq[ct][r] = fmaxf(zn, 0.f);
      }
      uint2 u; u.x = pk2(zq[ct][0], zq[ct][1]); u.y = pk2(zq[ct][2], zq[ct][3]);
      *(uint2*)&zqb[(16 * ct + c) * 72 + 16 * w + 4 * q4] = u;
    }
  }

  // store Z: rows 0..63 = q-part, rows 64..319 = m-part
#pragma unroll
  for (int ct = 0; ct < 2; ++ct)
#pragma unroll
    for (int r = 0; r < 4; ++r)
      Z[(16 * w + 4 * q4 + r) * NTOT + j0 + 16 * ct + c] = zq[ct][r];
#pragma unroll
  for (int rt = 0; rt < 4; ++rt)
#pragma unroll
    for (int ct = 0; ct < 2; ++ct)
#pragma unroll
      for (int r = 0; r < 4; ++r)
        Z[(64 + 64 * w + 16 * rt + 4 * q4 + r) * NTOT + j0 + 16 * ct + c] = zm[rt][ct][r];
}

extern "C" void kernel_launch(void* const* d_in, const int* in_sizes, int n_in,
                              void* d_out, int out_size, void* d_ws, size_t ws_size,
                              hipStream_t stream) {
  const float* X = (const float*)d_in[0];
  const float* D = (const float*)d_in[1];
  float* Z = (float*)d_out;
  rnmf_prep<<<dim3(1), dim3(256), 0, stream>>>(D, d_ws);
  rnmf_main<<<dim3(NTOT / NCOL), dim3(256), 0, stream>>>(X, Z, d_ws);
}

// Round 2
// 229.598 us; speedup vs baseline: 1.0599x; 1.0599x over previous
//
#include <hip/hip_runtime.h>

// RNMF encoder, MI355X. Identities:
//   b_k = b_0 + H z_k  (ISTA scan telescopes) => z <- relu(b0 + H z - t), 16x
//   H z = [(1-0.1*eta) z_q - eta*D^T(u+z_m) ; (1-1.1*eta) z_m - eta*u], u = D z_q
// eta = 1/lambda_max(D^T D) via on-device power method (G^8 squarings + 28 iters).
// R2: LDS overlay (xs dead after b0 -> zqb/vb alias it; 33KB -> 4 blk/CU),
//     zq/V stored in MFMA-B-fragment order (reads = base + lane*16, conflict-free),
//     packed f32x2 update math (v_pk_fma_f32) + cvt_pk_bf16_f32 packing.

typedef __bf16 bf16x8 __attribute__((ext_vector_type(8)));
typedef __bf16 bf16x2 __attribute__((ext_vector_type(2)));
typedef float f32x4 __attribute__((ext_vector_type(4)));
typedef float f32x2 __attribute__((ext_vector_type(2)));

#define MFMA16(a, b, c) __builtin_amdgcn_mfma_f32_16x16x32_bf16((a), (b), (c), 0, 0, 0)

#define NTOT 65536
#define NCOL 32

__device__ __forceinline__ unsigned pk2(float a, float b) {
#if __has_builtin(__builtin_amdgcn_cvt_pk_bf16_f32)
  return __builtin_bit_cast(unsigned, __builtin_amdgcn_cvt_pk_bf16_f32(a, b));
#else
  unsigned short ua = __builtin_bit_cast(unsigned short, (__bf16)a);
  unsigned short ub = __builtin_bit_cast(unsigned short, (__bf16)b);
  return (unsigned)ua | ((unsigned)ub << 16);
#endif
}
__device__ __forceinline__ unsigned pk2v(f32x2 v) { return pk2(v[0], v[1]); }
__device__ __forceinline__ f32x2 f2(float s) { f32x2 v = {s, s}; return v; }
__device__ __forceinline__ f32x2 pfma(f32x2 a, f32x2 b, f32x2 c) {
  return __builtin_elementwise_fma(a, b, c);
}
__device__ __forceinline__ f32x2 pmax0(f32x2 a) {
  return __builtin_elementwise_max(a, f2(0.f));
}

// ---------------- Kernel 0: prep (1 block, 256 threads) ----------------
// ws: [0..255] header (wsf[0]=eta), +256: Dbf [256][64] bf16, +256+32768: DTbf [64][256] bf16.
#define GOF(row) ((row) * 68 + (((row) >> 3) << 2))   // skewed fp32 row offset (16B-aligned)
__global__ void rnmf_prep(const float* __restrict__ D, void* __restrict__ ws) {
  float* wsf = (float*)ws;
  __bf16* Dbf = (__bf16*)((char*)ws + 256);
  __bf16* DTbf = (__bf16*)((char*)ws + 256 + 32768);

  __shared__ __bf16 DTl[64 * 264];   // D^T, [a][k] stride 264
  __shared__ __bf16 gA[64 * 72];
  __shared__ __bf16 gB[64 * 72];
  __shared__ float gf[64 * 68 + 32]; // G^8 fp32, skewed rows
  __shared__ __align__(16) float xv[64];

  const int tid = threadIdx.x;
  const int w = tid >> 6, lane = tid & 63, c = lane & 15, q4 = lane >> 4;

#pragma unroll
  for (int e = 0; e < 16; ++e) {
    int i4 = e * 256 + tid;
    float4 dv = *(const float4*)(D + i4 * 4);
    uint2 u; u.x = pk2(dv.x, dv.y); u.y = pk2(dv.z, dv.w);
    *(uint2*)(Dbf + i4 * 4) = u;
  }
#pragma unroll
  for (int e = 0; e < 64; ++e) {
    int flat = e * 256 + tid;
    int k = flat >> 6, a = flat & 63;
    DTl[a * 264 + k] = (__bf16)D[k * 64 + a];
  }
  __syncthreads();
#pragma unroll
  for (int e = 0; e < 8; ++e) {
    int fi = e * 256 + tid;
    int a = fi >> 5;
    int k = (fi * 8) & 255;
    *(bf16x8*)(DTbf + fi * 8) = *(const bf16x8*)&DTl[a * 264 + k];
  }
  // G = D^T D
#pragma unroll
  for (int ct = 0; ct < 4; ++ct) {
    f32x4 acc = {0.f, 0.f, 0.f, 0.f};
#pragma unroll
    for (int kb = 0; kb < 8; ++kb) {
      bf16x8 a = *(const bf16x8*)&DTl[(16 * w + c) * 264 + 32 * kb + 8 * q4];
      bf16x8 b = *(const bf16x8*)&DTl[(16 * ct + c) * 264 + 32 * kb + 8 * q4];
      acc = MFMA16(a, b, acc);
    }
#pragma unroll
    for (int r = 0; r < 4; ++r)
      gA[(16 * w + 4 * q4 + r) * 72 + 16 * ct + c] = (__bf16)acc[r];
  }
  __syncthreads();
  // G2
#pragma unroll
  for (int ct = 0; ct < 4; ++ct) {
    f32x4 acc = {0.f, 0.f, 0.f, 0.f};
#pragma unroll
    for (int kb = 0; kb < 2; ++kb) {
      bf16x8 a = *(const bf16x8*)&gA[(16 * w + c) * 72 + 32 * kb + 8 * q4];
      bf16x8 b = *(const bf16x8*)&gA[(16 * ct + c) * 72 + 32 * kb + 8 * q4];
      acc = MFMA16(a, b, acc);
    }
#pragma unroll
    for (int r = 0; r < 4; ++r)
      gB[(16 * w + 4 * q4 + r) * 72 + 16 * ct + c] = (__bf16)acc[r];
  }
  __syncthreads();
  // G4
#pragma unroll
  for (int ct = 0; ct < 4; ++ct) {
    f32x4 acc = {0.f, 0.f, 0.f, 0.f};
#pragma unroll
    for (int kb = 0; kb < 2; ++kb) {
      bf16x8 a = *(const bf16x8*)&gB[(16 * w + c) * 72 + 32 * kb + 8 * q4];
      bf16x8 b = *(const bf16x8*)&gB[(16 * ct + c) * 72 + 32 * kb + 8 * q4];
      acc = MFMA16(a, b, acc);
    }
#pragma unroll
    for (int r = 0; r < 4; ++r)
      gA[(16 * w + 4 * q4 + r) * 72 + 16 * ct + c] = (__bf16)acc[r];
  }
  __syncthreads();
  // G8 -> fp32
#pragma unroll
  for (int ct = 0; ct < 4; ++ct) {
    f32x4 acc = {0.f, 0.f, 0.f, 0.f};
#pragma unroll
    for (int kb = 0; kb < 2; ++kb) {
      bf16x8 a = *(const bf16x8*)&gA[(16 * w + c) * 72 + 32 * kb + 8 * q4];
      bf16x8 b = *(const bf16x8*)&gA[(16 * ct + c) * 72 + 32 * kb + 8 * q4];
      acc = MFMA16(a, b, acc);
    }
#pragma unroll
    for (int r = 0; r < 4; ++r)
      gf[GOF(16 * w + 4 * q4 + r) + 16 * ct + c] = acc[r];
  }
  __syncthreads();

  if (w == 0) {
    float td = gf[GOF(lane) + lane];
#pragma unroll
    for (int off = 32; off; off >>= 1) td += __shfl_xor(td, off, 64);
    const float tr = td;
    const float itr = 1.f / tr;
    xv[lane] = 1.f;
    float nm = 1.f;
    const int rowoff = GOF(lane);
    for (int itp = 0; itp < 28; ++itp) {
      float acc = 0.f;
#pragma unroll
      for (int k = 0; k < 64; k += 4) {
        float4 g = *(const float4*)&gf[rowoff + k];
        float4 xx = *(const float4*)&xv[k];
        acc = fmaf(g.x, xx.x, acc);
        acc = fmaf(g.y, xx.y, acc);
        acc = fmaf(g.z, xx.z, acc);
        acc = fmaf(g.w, xx.w, acc);
      }
      float y = acc * itr;
      float n2 = y * y;
#pragma unroll
      for (int off = 32; off; off >>= 1) n2 += __shfl_xor(n2, off, 64);
      nm = sqrtf(n2);
      xv[lane] = y / nm;
    }
    if (lane == 0) wsf[0] = 1.f / powf(nm * tr, 0.125f);  // eta = 1/alpha
  }
}

// ---------------- Kernel 1: main (2048 blocks x 256 thr, 32 cols/block) -----
// LDS arena overlay:
//   phase A: xs = fp32 X tile [col][row], stride 260  (33280 B)
//   phase B: zqb = zq in B-frag order [ct][kb<2][q4][n][j]  (4096 B at +0)
//            vb  = V  in B-frag order [ct][kb<8][q4][n][j]  (16384 B at +4096)
__global__ __launch_bounds__(256, 3) void rnmf_main(const float* __restrict__ X,
                                                    float* __restrict__ Z,
                                                    const void* __restrict__ ws) {
  const float* wsf = (const float*)ws;
  const __bf16* Dbf = (const __bf16*)((const char*)ws + 256);
  const __bf16* DTbf = (const __bf16*)((const char*)ws + 256 + 32768);

  __shared__ __align__(16) char arena[33280];
  float* xs = (float*)arena;

  const int tid = threadIdx.x;
  const int w = tid >> 6;
  const int lane = tid & 63;
  const int c = lane & 15;
  const int q4 = lane >> 4;
  const int q4h = q4 >> 1, q4l = q4 & 1;
  const int j0 = blockIdx.x * NCOL;

  // stage X tile: coalesced float4 global loads, scalar LDS scatter (one-time)
#pragma unroll
  for (int e = 0; e < 8; ++e) {
    int idx = e * 256 + tid;                  // float4 id, 2048 total
    int row = idx >> 3, c4 = (idx & 7) * 4;
    float4 g = *(const float4*)(X + row * NTOT + j0 + c4);
    xs[(c4 + 0) * 260 + row] = g.x;
    xs[(c4 + 1) * 260 + row] = g.y;
    xs[(c4 + 2) * 260 + row] = g.z;
    xs[(c4 + 3) * 260 + row] = g.w;
  }

  const float eta = wsf[0];
  const f32x2 etav = f2(eta);
  const f32x2 metav = f2(-eta);
  const f32x2 cqv = f2(1.f - 0.1f * eta);
  const f32x2 cmv = f2(1.f - 1.1f * eta);
  const float tm = 0.1f * eta;

  // D fragments (iteration-invariant, VGPR-resident)
  bf16x8 d1[4][2];   // GEMM1 A: D rows [64w..64w+64), K=64
#pragma unroll
  for (int rt = 0; rt < 4; ++rt)
#pragma unroll
    for (int kb = 0; kb < 2; ++kb)
      d1[rt][kb] = *(const bf16x8*)(Dbf + (64 * w + 16 * rt + c) * 64 + 32 * kb + 8 * q4);
  bf16x8 d2[8];      // GEMM2 A: D^T rows [16w..16w+16), K=256
#pragma unroll
  for (int kb = 0; kb < 8; ++kb)
    d2[kb] = *(const bf16x8*)(DTbf + (16 * w + c) * 256 + 32 * kb + 8 * q4);

  __syncthreads();   // xs staged

  // b0_q = eta * D^T x
  f32x2 bqt2[2][2];
#pragma unroll
  for (int ct = 0; ct < 2; ++ct) {
    f32x4 acc = {0.f, 0.f, 0.f, 0.f};
#pragma unroll
    for (int kb = 0; kb < 8; ++kb) {
      const float* p = &xs[(16 * ct + c) * 260 + 32 * kb + 8 * q4];
      float4 lo = *(const float4*)p;
      float4 hi = *(const float4*)(p + 4);
      unsigned p0 = pk2(lo.x, lo.y), p1 = pk2(lo.z, lo.w);
      unsigned p2 = pk2(hi.x, hi.y), p3 = pk2(hi.z, hi.w);
      uint4 packed = {p0, p1, p2, p3};
      acc = MFMA16(d2[kb], __builtin_bit_cast(bf16x8, packed), acc);
    }
    f32x2 a0 = {acc[0], acc[1]}, a1 = {acc[2], acc[3]};
    bqt2[ct][0] = etav * a0;   // t_q = 0
    bqt2[ct][1] = etav * a1;
  }

  // b0_m - t_m = eta*x - tm (exact fp32)
  f32x2 bmt2[4][2][2];
#pragma unroll
  for (int rt = 0; rt < 4; ++rt)
#pragma unroll
    for (int ct = 0; ct < 2; ++ct) {
      const float* p = &xs[(16 * ct + c) * 260 + 64 * w + 16 * rt + 4 * q4];
      float4 v = *(const float4*)p;
      f32x2 x0 = {v.x, v.y}, x1 = {v.z, v.w};
      bmt2[rt][ct][0] = pfma(etav, x0, f2(-tm));
      bmt2[rt][ct][1] = pfma(etav, x1, f2(-tm));
    }

  __syncthreads();   // xs dead -> arena reusable as zqb/vb

  // z1 = relu(b0 - t)
  f32x2 zq2[2][2], zm2[4][2][2];
#pragma unroll
  for (int ct = 0; ct < 2; ++ct)
#pragma unroll
    for (int p = 0; p < 2; ++p) zq2[ct][p] = pmax0(bqt2[ct][p]);
#pragma unroll
  for (int rt = 0; rt < 4; ++rt)
#pragma unroll
    for (int ct = 0; ct < 2; ++ct)
#pragma unroll
      for (int p = 0; p < 2; ++p) zm2[rt][ct][p] = pmax0(bmt2[rt][ct][p]);

  // per-lane LDS byte offsets (B-frag layouts; reads are base + lane*16)
  char* smem = arena;
  const int rb = lane * 16;                                          // read base
  const int wzq = (w >> 1) * 1024 + ((2 * w) & 3) * 256 + q4h * 256 + c * 16 + 8 * q4l;
  const int wvb = 4096 + 2 * w * 1024 + q4h * 256 + c * 16 + 8 * q4l;

  // publish z1_q
#pragma unroll
  for (int ct = 0; ct < 2; ++ct) {
    uint2 u; u.x = pk2v(zq2[ct][0]); u.y = pk2v(zq2[ct][1]);
    *(uint2*)(smem + wzq + ct * 2048) = u;
  }

  for (int it = 0; it < 15; ++it) {
    __syncthreads();   // zqb ready; vb free
    // GEMM1: U = D z_q ; z_m update ; publish V = u + z_m(old)
#pragma unroll
    for (int ct = 0; ct < 2; ++ct) {
      bf16x8 bz0 = *(const bf16x8*)(smem + rb + ct * 2048);
      bf16x8 bz1 = *(const bf16x8*)(smem + rb + ct * 2048 + 1024);
#pragma unroll
      for (int rt = 0; rt < 4; ++rt) {
        f32x4 acc = {0.f, 0.f, 0.f, 0.f};
        acc = MFMA16(d1[rt][0], bz0, acc);
        acc = MFMA16(d1[rt][1], bz1, acc);
        f32x2 u0 = {acc[0], acc[1]}, u1 = {acc[2], acc[3]};
        f32x2 z0 = zm2[rt][ct][0], z1 = zm2[rt][ct][1];
        f32x2 v0 = u0 + z0, v1 = u1 + z1;
        f32x2 t0 = pfma(cmv, z0, bmt2[rt][ct][0]);
        f32x2 t1 = pfma(cmv, z1, bmt2[rt][ct][1]);
        zm2[rt][ct][0] = pmax0(pfma(metav, u0, t0));
        zm2[rt][ct][1] = pmax0(pfma(metav, u1, t1));
        uint2 uu; uu.x = pk2v(v0); uu.y = pk2v(v1);
        *(uint2*)(smem + wvb + ct * 8192 + rt * 512) = uu;
      }
    }
    __syncthreads();   // vb ready; zqb free
    // GEMM2: w = D^T V ; z_q update ; publish
#pragma unroll
    for (int ct = 0; ct < 2; ++ct) {
      f32x4 acc = {0.f, 0.f, 0.f, 0.f};
#pragma unroll
      for (int kb = 0; kb < 8; ++kb) {
        bf16x8 bv = *(const bf16x8*)(smem + rb + 4096 + ct * 8192 + kb * 1024);
        acc = MFMA16(d2[kb], bv, acc);
      }
      f32x2 w0 = {acc[0], acc[1]}, w1 = {acc[2], acc[3]};
      f32x2 t0 = pfma(cqv, zq2[ct][0], bqt2[ct][0]);
      f32x2 t1 = pfma(cqv, zq2[ct][1], bqt2[ct][1]);
      zq2[ct][0] = pmax0(pfma(metav, w0, t0));
      zq2[ct][1] = pmax0(pfma(metav, w1, t1));
      uint2 u; u.x = pk2v(zq2[ct][0]); u.y = pk2v(zq2[ct][1]);
      *(uint2*)(smem + wzq + ct * 2048) = u;
    }
  }

  // store Z: rows 0..63 = q-part, rows 64..319 = m-part
#pragma unroll
  for (int ct = 0; ct < 2; ++ct)
#pragma unroll
    for (int p = 0; p < 2; ++p)
#pragma unroll
      for (int e = 0; e < 2; ++e)
        Z[(16 * w + 4 * q4 + 2 * p + e) * NTOT + j0 + 16 * ct + c] = zq2[ct][p][e];
#pragma unroll
  for (int rt = 0; rt < 4; ++rt)
#pragma unroll
    for (int ct = 0; ct < 2; ++ct)
#pragma unroll
      for (int p = 0; p < 2; ++p)
#pragma unroll
        for (int e = 0; e < 2; ++e)
          Z[(64 + 64 * w + 16 * rt + 4 * q4 + 2 * p + e) * NTOT + j0 + 16 * ct + c] = zm2[rt][ct][p][e];
}

extern "C" void kernel_launch(void* const* d_in, const int* in_sizes, int n_in,
                              void* d_out, int out_size, void* d_ws, size_t ws_size,
                              hipStream_t stream) {
  const float* X = (const float*)d_in[0];
  const float* D = (const float*)d_in[1];
  float* Z = (float*)d_out;
  rnmf_prep<<<dim3(1), dim3(256), 0, stream>>>(D, d_ws);
  rnmf_main<<<dim3(NTOT / NCOL), dim3(256), 0, stream>>>(X, Z, d_ws);
}